// Round 7
// baseline (2933.348 us; speedup 1.0000x reference)
//
#include <hip/hip_runtime.h>

#define N_NODES 100000
#define N_EDGES 1600000
#define FEAT 64
#define BSHIFT 7
#define NPB 128                                   // nodes per bucket
#define NBUCK ((N_NODES + NPB - 1) / NPB)         // 782
#define AGG_LD 68                                 // padded LDS row stride (bank spread)

#define HIST_TILE 8192
#define HIST_BLOCKS ((N_EDGES + HIST_TILE - 1) / HIST_TILE)     // 196
#define SPLIT_TILE 16384
#define SPLIT_BLOCKS ((N_EDGES + SPLIT_TILE - 1) / SPLIT_TILE)  // 98

// ---- bucket histogram: per-block LDS hist, ONE global atomic per (block,bucket)
__global__ __launch_bounds__(256) void hist_kernel(const int* __restrict__ dst,
                                                   int* __restrict__ ghist) {
    __shared__ int h[NBUCK];
    for (int t = threadIdx.x; t < NBUCK; t += 256) h[t] = 0;
    __syncthreads();
    int beg = blockIdx.x * HIST_TILE;
    int end = min(beg + HIST_TILE, N_EDGES);
    for (int i = beg + threadIdx.x; i < end; i += 256)
        atomicAdd(&h[dst[i] >> BSHIFT], 1);
    __syncthreads();
    for (int t = threadIdx.x; t < NBUCK; t += 256)
        if (h[t]) atomicAdd(&ghist[t], h[t]);
}

// ---- exclusive scan of 782 bucket counts (single block, 1024 thr)
__global__ __launch_bounds__(1024) void scan_buckets(const int* __restrict__ ghist,
                                                     int* __restrict__ base,
                                                     int* __restrict__ cursor) {
    __shared__ int sdata[1024];
    int t = threadIdx.x;
    int v = (t < NBUCK) ? ghist[t] : 0;
    sdata[t] = v;
    __syncthreads();
    for (int off = 1; off < 1024; off <<= 1) {
        int add = (t >= off) ? sdata[t - off] : 0;
        __syncthreads();
        sdata[t] += add;
        __syncthreads();
    }
    if (t < NBUCK) { int ex = sdata[t] - v; base[t] = ex; cursor[t] = ex; }
    if (t == 0) base[NBUCK] = N_EDGES;
}

// ---- multisplit: block reserves dense per-bucket regions (one global atomic per
// (block,bucket)), then writes packed edges burst-clustered -> full cache lines.
// pk = (dst&127)<<17 | src   (src < 2^17, dl < 2^7)
__global__ __launch_bounds__(256) void split_kernel(const int* __restrict__ src,
                                                    const int* __restrict__ dst,
                                                    int* __restrict__ cursor,
                                                    int* __restrict__ pk) {
    __shared__ int h[NBUCK];
    __shared__ int lb[NBUCK];
    for (int t = threadIdx.x; t < NBUCK; t += 256) h[t] = 0;
    __syncthreads();
    int beg = blockIdx.x * SPLIT_TILE;
    int end = min(beg + SPLIT_TILE, N_EDGES);
    for (int i = beg + threadIdx.x; i < end; i += 256)
        atomicAdd(&h[dst[i] >> BSHIFT], 1);
    __syncthreads();
    for (int t = threadIdx.x; t < NBUCK; t += 256)
        lb[t] = h[t] ? atomicAdd(&cursor[t], h[t]) : 0;
    __syncthreads();
    for (int t = threadIdx.x; t < NBUCK; t += 256) h[t] = 0;
    __syncthreads();
    for (int i = beg + threadIdx.x; i < end; i += 256) {
        int d = dst[i];
        int b = d >> BSHIFT;
        int off = atomicAdd(&h[b], 1);
        pk[lb[b] + off] = ((d & (NPB - 1)) << 17) | src[i];
    }
}

// ---- fused GIN layer: one block per bucket. Aggregate 128 node rows in LDS via
// ds f32 atomics (lane map: g=edge slot, c=float4 chunk -> 1KB gather per wave
// instr), then self + readlane matmul (+bias, optional ReLU).
template <int OUTF, bool RELU>
__global__ __launch_bounds__(256) void gin_fused(
    const float* __restrict__ in, const int* __restrict__ base,
    const int* __restrict__ pk, const float* __restrict__ W,
    const float* __restrict__ bias, float* __restrict__ out) {
    __shared__ float agg[NPB * AGG_LD];
    const int lane = threadIdx.x & 63;
    const int wave = threadIdx.x >> 6;   // 0..3
    const int g = lane >> 4, c = lane & 15;
    const int b = blockIdx.x;
    const int node0 = b << BSHIFT;

    // lane j holds W row j (output feature j)
    const int jc = (OUTF == 64) ? lane : ((lane < OUTF) ? lane : 0);
    float Wc[64];
#pragma unroll
    for (int k = 0; k < 16; ++k) {
        float4 w4 = ((const float4*)(W + jc * 64))[k];
        Wc[4 * k + 0] = w4.x; Wc[4 * k + 1] = w4.y;
        Wc[4 * k + 2] = w4.z; Wc[4 * k + 3] = w4.w;
    }
    const float bj = bias[jc];

    for (int t = threadIdx.x; t < NPB * AGG_LD; t += 256) agg[t] = 0.0f;
    __syncthreads();

    const float4* inv = (const float4*)in;
    const int ebeg = base[b], eend = base[b + 1];
    for (int e = ebeg + wave * 4; e < eend; e += 16) {
        int idx = e + g;
        if (idx < eend) {
            int p = pk[idx];
            int s = p & 0x1FFFF;
            int dl = p >> 17;
            float4 v = inv[(size_t)s * 16 + c];
            float* arow = &agg[dl * AGG_LD + 4 * c];
            atomicAdd(&arow[0], v.x);
            atomicAdd(&arow[1], v.y);
            atomicAdd(&arow[2], v.z);
            atomicAdd(&arow[3], v.w);
        }
    }
    __syncthreads();

    for (int nl = wave; nl < NPB; nl += 4) {
        int node = node0 + nl;
        if (node >= N_NODES) break;                      // wave-uniform
        float r = in[(size_t)node * 64 + lane] + agg[nl * AGG_LD + lane];
        float acc = bj;
#pragma unroll
        for (int k = 0; k < 64; ++k) {
            float rv = __int_as_float(__builtin_amdgcn_readlane(__float_as_int(r), k));
            acc = fmaf(rv, Wc[k], acc);
        }
        if (OUTF == 64) {
            out[(size_t)node * 64 + lane] = RELU ? fmaxf(acc, 0.0f) : acc;
        } else if (lane < OUTF) {
            out[(size_t)node * OUTF + lane] = RELU ? fmaxf(acc, 0.0f) : acc;
        }
    }
}

// ---------------- launcher ----------------

extern "C" void kernel_launch(void* const* d_in, const int* in_sizes, int n_in,
                              void* d_out, int out_size, void* d_ws, size_t ws_size,
                              hipStream_t stream) {
    const float* x  = (const float*)d_in[0];
    const int*   ei = (const int*)d_in[1];
    const int*   src = ei;
    const int*   dst = ei + N_EDGES;
    const float* W1 = (const float*)d_in[2];
    const float* b1 = (const float*)d_in[3];
    const float* W2 = (const float*)d_in[4];
    const float* b2 = (const float*)d_in[5];
    const float* W3 = (const float*)d_in[6];
    const float* b3 = (const float*)d_in[7];
    const float* W4 = (const float*)d_in[8];
    const float* b4 = (const float*)d_in[9];
    float* out = (float*)d_out;

    char* ws = (char*)d_ws;
    size_t off = 0;
    auto carve = [&](size_t bytes) {
        char* p = ws + off;
        off += (bytes + 255) & ~(size_t)255;
        return p;
    };
    int* ghist   = (int*)carve(NBUCK * sizeof(int));
    int* base    = (int*)carve((NBUCK + 1) * sizeof(int));
    int* cursor  = (int*)carve(NBUCK * sizeof(int));
    int* pk      = (int*)carve((size_t)N_EDGES * sizeof(int));
    float* h1    = (float*)carve((size_t)N_NODES * FEAT * sizeof(float));
    float* h2    = (float*)carve((size_t)N_NODES * FEAT * sizeof(float));
    (void)ws_size;

    hipMemsetAsync(ghist, 0, NBUCK * sizeof(int), stream);
    hist_kernel<<<HIST_BLOCKS, 256, 0, stream>>>(dst, ghist);
    scan_buckets<<<1, 1024, 0, stream>>>(ghist, base, cursor);
    split_kernel<<<SPLIT_BLOCKS, 256, 0, stream>>>(src, dst, cursor, pk);

    gin_fused<64, true ><<<NBUCK, 256, 0, stream>>>(x,  base, pk, W1, b1, h1);
    gin_fused<64, true ><<<NBUCK, 256, 0, stream>>>(h1, base, pk, W2, b2, h2);
    gin_fused<64, true ><<<NBUCK, 256, 0, stream>>>(h2, base, pk, W3, b3, h1);
    gin_fused<10, false><<<NBUCK, 256, 0, stream>>>(h1, base, pk, W4, b4, out);
}

// Round 10
// 560.678 us; speedup vs baseline: 5.2318x; 5.2318x over previous
//
#include <hip/hip_runtime.h>

#define N_NODES 100000
#define N_EDGES 1600000
#define FEAT 64
#define BSHIFT 7
#define NPB 128                                   // nodes per bucket
#define NBUCK ((N_NODES + NPB - 1) / NPB)         // 782

#define HIST_TILE 8192
#define HIST_BLOCKS ((N_EDGES + HIST_TILE - 1) / HIST_TILE)     // 196
#define SPLIT_TILE 16384
#define SPLIT_BLOCKS ((N_EDGES + SPLIT_TILE - 1) / SPLIT_TILE)  // 98

// ---- bucket histogram: per-block LDS hist, ONE global atomic per (block,bucket)
__global__ __launch_bounds__(256) void hist_kernel(const int* __restrict__ dst,
                                                   int* __restrict__ ghist) {
    __shared__ int h[NBUCK];
    for (int t = threadIdx.x; t < NBUCK; t += 256) h[t] = 0;
    __syncthreads();
    int beg = blockIdx.x * HIST_TILE;
    int end = min(beg + HIST_TILE, N_EDGES);
    for (int i = beg + threadIdx.x; i < end; i += 256)
        atomicAdd(&h[dst[i] >> BSHIFT], 1);
    __syncthreads();
    for (int t = threadIdx.x; t < NBUCK; t += 256)
        if (h[t]) atomicAdd(&ghist[t], h[t]);
}

// ---- exclusive scan of 782 bucket counts (single block, 1024 thr)
__global__ __launch_bounds__(1024) void scan_buckets(const int* __restrict__ ghist,
                                                     int* __restrict__ base,
                                                     int* __restrict__ cursor) {
    __shared__ int sdata[1024];
    int t = threadIdx.x;
    int v = (t < NBUCK) ? ghist[t] : 0;
    sdata[t] = v;
    __syncthreads();
    for (int off = 1; off < 1024; off <<= 1) {
        int add = (t >= off) ? sdata[t - off] : 0;
        __syncthreads();
        sdata[t] += add;
        __syncthreads();
    }
    if (t < NBUCK) { int ex = sdata[t] - v; base[t] = ex; cursor[t] = ex; }
    if (t == 0) base[NBUCK] = N_EDGES;
}

// ---- multisplit: block reserves dense per-bucket regions (one global atomic per
// (block,bucket)), then writes packed edges burst-clustered -> full cache lines.
// pk = (dst&127)<<17 | src   (src < 2^17, dl < 2^7)
__global__ __launch_bounds__(256) void split_kernel(const int* __restrict__ src,
                                                    const int* __restrict__ dst,
                                                    int* __restrict__ cursor,
                                                    int* __restrict__ pk) {
    __shared__ int h[NBUCK];
    __shared__ int lb[NBUCK];
    for (int t = threadIdx.x; t < NBUCK; t += 256) h[t] = 0;
    __syncthreads();
    int beg = blockIdx.x * SPLIT_TILE;
    int end = min(beg + SPLIT_TILE, N_EDGES);
    for (int i = beg + threadIdx.x; i < end; i += 256)
        atomicAdd(&h[dst[i] >> BSHIFT], 1);
    __syncthreads();
    for (int t = threadIdx.x; t < NBUCK; t += 256)
        lb[t] = h[t] ? atomicAdd(&cursor[t], h[t]) : 0;
    __syncthreads();
    for (int t = threadIdx.x; t < NBUCK; t += 256) h[t] = 0;
    __syncthreads();
    for (int i = beg + threadIdx.x; i < end; i += 256) {
        int d = dst[i];
        int b = d >> BSHIFT;
        int off = atomicAdd(&h[b], 1);
        pk[lb[b] + off] = ((d & (NPB - 1)) << 17) | src[i];
    }
}

// ---- per-bucket CSR finalize: LDS count/scan/place. Dense reads+writes within
// the bucket's ~8KB region; no global atomics.
__global__ __launch_bounds__(256) void bucket_csr(const int* __restrict__ pk,
                                                  const int* __restrict__ base,
                                                  int* __restrict__ row_start,
                                                  int* __restrict__ src_sorted) {
    __shared__ int cnt[NPB];
    __shared__ int cur[NPB];
    const int b = blockIdx.x;
    const int node0 = b << BSHIFT;
    const int ebeg = base[b], eend = base[b + 1];
    int t = threadIdx.x;
    if (t < NPB) cnt[t] = 0;
    __syncthreads();
    for (int e = ebeg + t; e < eend; e += 256)
        atomicAdd(&cnt[pk[e] >> 17], 1);
    __syncthreads();
    // Hillis-Steele inclusive scan over 128 entries (threads 0..127)
    int v = (t < NPB) ? cnt[t] : 0;
    for (int off = 1; off < NPB; off <<= 1) {
        int add = (t < NPB && t >= off) ? cnt[t - off] : 0;
        __syncthreads();
        if (t < NPB) cnt[t] += add;
        __syncthreads();
    }
    if (t < NPB) {
        int incl = cnt[t];
        int excl = incl - v;
        cur[t] = excl;
        int node = node0 + t;
        if (node < N_NODES) row_start[node] = ebeg + excl;
    }
    if (b == NBUCK - 1 && t == 0) row_start[N_NODES] = N_EDGES;
    __syncthreads();
    for (int e = ebeg + t; e < eend; e += 256) {
        int p = pk[e];
        int off = atomicAdd(&cur[p >> 17], 1);
        src_sorted[ebeg + off] = p & 0x1FFFF;
    }
}

// ---- fused GIN hidden layer (measured-good architecture) ----
// One wave per node. Lane map: g = lane>>4 (edge slot), c = lane&15 (float4
// chunk). 1KB gather per wave-instr, 2 independent chains. Then readlane
// matmul with W row per-lane. ReLU.
template <int OUTF, bool RELU>
__global__ __launch_bounds__(256) void gin_layer(
    const float* __restrict__ in, const int* __restrict__ row_start,
    const int* __restrict__ src_sorted, const float* __restrict__ W,
    const float* __restrict__ bias, float* __restrict__ out, int n_nodes) {
    const int lane = threadIdx.x & 63;
    const int g = lane >> 4;
    const int c = lane & 15;
    int wid = (int)((blockIdx.x * blockDim.x + threadIdx.x) >> 6);
    const int nw = (int)((gridDim.x * blockDim.x) >> 6);
    wid = __builtin_amdgcn_readfirstlane(wid);

    const float4* inv = (const float4*)in;

    const int jc = (OUTF == 64) ? lane : ((lane < OUTF) ? lane : 0);
    float Wc[64];
#pragma unroll
    for (int k = 0; k < 16; ++k) {
        float4 w4 = ((const float4*)(W + jc * 64))[k];
        Wc[4 * k + 0] = w4.x; Wc[4 * k + 1] = w4.y;
        Wc[4 * k + 2] = w4.z; Wc[4 * k + 3] = w4.w;
    }
    const float bj = bias[jc];

    for (int node = wid; node < n_nodes; node += nw) {
        const int e0 = row_start[node];
        const int e1 = row_start[node + 1];

        float4 a0 = make_float4(0.f, 0.f, 0.f, 0.f);
        float4 a1 = make_float4(0.f, 0.f, 0.f, 0.f);
        if (g == 0) a0 = inv[(size_t)node * 16 + c];

        for (int e = e0; e < e1; e += 8) {
            int i0 = e + g;
            int i1 = e + g + 4;
            if (i0 < e1) {
                int s = src_sorted[i0];
                float4 v = inv[(size_t)s * 16 + c];
                a0.x += v.x; a0.y += v.y; a0.z += v.z; a0.w += v.w;
            }
            if (i1 < e1) {
                int s = src_sorted[i1];
                float4 v = inv[(size_t)s * 16 + c];
                a1.x += v.x; a1.y += v.y; a1.z += v.z; a1.w += v.w;
            }
        }
        a0.x += a1.x; a0.y += a1.y; a0.z += a1.z; a0.w += a1.w;

        a0.x += __shfl_xor(a0.x, 16); a0.y += __shfl_xor(a0.y, 16);
        a0.z += __shfl_xor(a0.z, 16); a0.w += __shfl_xor(a0.w, 16);
        a0.x += __shfl_xor(a0.x, 32); a0.y += __shfl_xor(a0.y, 32);
        a0.z += __shfl_xor(a0.z, 32); a0.w += __shfl_xor(a0.w, 32);

        float acc = bj;
#pragma unroll
        for (int cc = 0; cc < 16; ++cc) {
            float vx = __int_as_float(__builtin_amdgcn_readlane(__float_as_int(a0.x), cc));
            float vy = __int_as_float(__builtin_amdgcn_readlane(__float_as_int(a0.y), cc));
            float vz = __int_as_float(__builtin_amdgcn_readlane(__float_as_int(a0.z), cc));
            float vw = __int_as_float(__builtin_amdgcn_readlane(__float_as_int(a0.w), cc));
            acc = fmaf(vx, Wc[4 * cc + 0], acc);
            acc = fmaf(vy, Wc[4 * cc + 1], acc);
            acc = fmaf(vz, Wc[4 * cc + 2], acc);
            acc = fmaf(vw, Wc[4 * cc + 3], acc);
        }
        if (OUTF == 64 || lane < OUTF) {
            out[(size_t)node * OUTF + lane] = RELU ? fmaxf(acc, 0.0f) : acc;
        }
    }
}

// ---- head GEMM: z = h @ W4^T (no bias), 16-padded rows. Wave per node.
__global__ __launch_bounds__(256) void head_gemm(const float* __restrict__ in,
                                                 const float* __restrict__ W,
                                                 float* __restrict__ z) {
    const int lane = threadIdx.x & 63;
    int wid = (int)((blockIdx.x * blockDim.x + threadIdx.x) >> 6);
    const int nw = (int)((gridDim.x * blockDim.x) >> 6);
    wid = __builtin_amdgcn_readfirstlane(wid);

    const int jc = (lane < 10) ? lane : 0;
    float Wc[64];
#pragma unroll
    for (int k = 0; k < 16; ++k) {
        float4 w4 = ((const float4*)(W + jc * 64))[k];
        Wc[4 * k + 0] = w4.x; Wc[4 * k + 1] = w4.y;
        Wc[4 * k + 2] = w4.z; Wc[4 * k + 3] = w4.w;
    }

    for (int node = wid; node < N_NODES; node += nw) {
        float r = in[(size_t)node * 64 + lane];
        float acc = 0.0f;
#pragma unroll
        for (int k = 0; k < 64; ++k) {
            float rv = __int_as_float(__builtin_amdgcn_readlane(__float_as_int(r), k));
            acc = fmaf(rv, Wc[k], acc);
        }
        if (lane < 16) z[(size_t)node * 16 + lane] = (lane < 10) ? acc : 0.0f;
    }
}

// ---- head aggregate: out_i = z_i + sum_j z_j + b (10 of 16-padded feats).
// Lane map: g = lane>>4 (edge slot 0..3), c = lane&15 (feature). 8 edges in flight.
__global__ __launch_bounds__(256) void head_agg(const float* __restrict__ z,
                                                const int* __restrict__ row_start,
                                                const int* __restrict__ src_sorted,
                                                const float* __restrict__ bias,
                                                float* __restrict__ out) {
    const int lane = threadIdx.x & 63;
    const int g = lane >> 4;
    const int c = lane & 15;
    int wid = (int)((blockIdx.x * blockDim.x + threadIdx.x) >> 6);
    const int nw = (int)((gridDim.x * blockDim.x) >> 6);
    wid = __builtin_amdgcn_readfirstlane(wid);

    const float bc = (c < 10) ? bias[c] : 0.0f;

    for (int node = wid; node < N_NODES; node += nw) {
        const int e0 = row_start[node];
        const int e1 = row_start[node + 1];
        float a0 = 0.0f, a1 = 0.0f;
        if (g == 0) a0 = z[(size_t)node * 16 + c];
        for (int e = e0; e < e1; e += 8) {
            int i0 = e + g;
            int i1 = e + g + 4;
            if (i0 < e1) a0 += z[(size_t)src_sorted[i0] * 16 + c];
            if (i1 < e1) a1 += z[(size_t)src_sorted[i1] * 16 + c];
        }
        a0 += a1;
        a0 += __shfl_xor(a0, 16);
        a0 += __shfl_xor(a0, 32);
        if (g == 0 && c < 10) out[(size_t)node * 10 + c] = a0 + bc;
    }
}

// ---------------- launcher ----------------

extern "C" void kernel_launch(void* const* d_in, const int* in_sizes, int n_in,
                              void* d_out, int out_size, void* d_ws, size_t ws_size,
                              hipStream_t stream) {
    const float* x  = (const float*)d_in[0];
    const int*   ei = (const int*)d_in[1];
    const int*   src = ei;
    const int*   dst = ei + N_EDGES;
    const float* W1 = (const float*)d_in[2];
    const float* b1 = (const float*)d_in[3];
    const float* W2 = (const float*)d_in[4];
    const float* b2 = (const float*)d_in[5];
    const float* W3 = (const float*)d_in[6];
    const float* b3 = (const float*)d_in[7];
    const float* W4 = (const float*)d_in[8];
    const float* b4 = (const float*)d_in[9];
    float* out = (float*)d_out;

    char* ws = (char*)d_ws;
    size_t off = 0;
    auto carve = [&](size_t bytes) {
        char* p = ws + off;
        off += (bytes + 255) & ~(size_t)255;
        return p;
    };
    int* ghist      = (int*)carve(NBUCK * sizeof(int));
    int* base       = (int*)carve((NBUCK + 1) * sizeof(int));
    int* cursor     = (int*)carve(NBUCK * sizeof(int));
    int* row_start  = (int*)carve((N_NODES + 1) * sizeof(int));
    int* pk         = (int*)carve((size_t)N_EDGES * sizeof(int));
    int* src_sorted = (int*)carve((size_t)N_EDGES * sizeof(int));
    float* h1       = (float*)carve((size_t)N_NODES * FEAT * sizeof(float));
    float* h2       = (float*)carve((size_t)N_NODES * FEAT * sizeof(float));
    // z4 (100K x 16 f32 = 6.4MB) aliases pk: pk dead after bucket_csr
    float* z4       = (float*)pk;
    (void)ws_size;

    hipMemsetAsync(ghist, 0, NBUCK * sizeof(int), stream);
    hist_kernel<<<HIST_BLOCKS, 256, 0, stream>>>(dst, ghist);
    scan_buckets<<<1, 1024, 0, stream>>>(ghist, base, cursor);
    split_kernel<<<SPLIT_BLOCKS, 256, 0, stream>>>(src, dst, cursor, pk);
    bucket_csr<<<NBUCK, 256, 0, stream>>>(pk, base, row_start, src_sorted);

    gin_layer<64, true><<<2048, 256, 0, stream>>>(x,  row_start, src_sorted, W1, b1, h1, N_NODES);
    gin_layer<64, true><<<2048, 256, 0, stream>>>(h1, row_start, src_sorted, W2, b2, h2, N_NODES);
    gin_layer<64, true><<<2048, 256, 0, stream>>>(h2, row_start, src_sorted, W3, b3, h1, N_NODES);
    head_gemm<<<1024, 256, 0, stream>>>(h1, W4, z4);
    head_agg<<<2048, 256, 0, stream>>>(z4, row_start, src_sorted, b4, out);
}

// Round 11
// 517.616 us; speedup vs baseline: 5.6670x; 1.0832x over previous
//
#include <hip/hip_runtime.h>

#define N_NODES 100000
#define N_EDGES 1600000
#define BSHIFT 7
#define NPB 128                                   // nodes per bucket
#define NBUCK ((N_NODES + NPB - 1) / NPB)         // 782

#define SPLIT_TILE 16384
#define SPLIT_BLOCKS ((N_EDGES + SPLIT_TILE - 1) / SPLIT_TILE)  // 98

__device__ __forceinline__ unsigned short f2bf(float f) {
    unsigned u = __float_as_uint(f);
    unsigned r = (u + 0x7FFFu + ((u >> 16) & 1u)) >> 16;
    return (unsigned short)r;
}
__device__ __forceinline__ float bf2f(unsigned short s) {
    return __uint_as_float((unsigned)s << 16);
}
__device__ __forceinline__ void acc8(float* a, uint4 v) {
    a[0] += __uint_as_float(v.x << 16);
    a[1] += __uint_as_float(v.x & 0xFFFF0000u);
    a[2] += __uint_as_float(v.y << 16);
    a[3] += __uint_as_float(v.y & 0xFFFF0000u);
    a[4] += __uint_as_float(v.z << 16);
    a[5] += __uint_as_float(v.z & 0xFFFF0000u);
    a[6] += __uint_as_float(v.w << 16);
    a[7] += __uint_as_float(v.w & 0xFFFF0000u);
}

// ---- x (f32) -> xb (bf16), vectorized
__global__ __launch_bounds__(256) void cast_to_bf16(const float4* __restrict__ in,
                                                    ushort4* __restrict__ outv, int n4) {
    int i = blockIdx.x * 256 + threadIdx.x;
    int stride = gridDim.x * 256;
    for (; i < n4; i += stride) {
        float4 v = in[i];
        ushort4 o;
        o.x = f2bf(v.x); o.y = f2bf(v.y); o.z = f2bf(v.z); o.w = f2bf(v.w);
        outv[i] = o;
    }
}

// ---- bucket histogram: 64 blocks grid-stride -> global-atomic chain/bucket = 64
__global__ __launch_bounds__(256) void hist_kernel(const int* __restrict__ dst,
                                                   int* __restrict__ ghist) {
    __shared__ int h[NBUCK];
    for (int t = threadIdx.x; t < NBUCK; t += 256) h[t] = 0;
    __syncthreads();
    int i = blockIdx.x * 256 + threadIdx.x;
    int stride = gridDim.x * 256;
    for (; i < N_EDGES; i += stride) atomicAdd(&h[dst[i] >> BSHIFT], 1);
    __syncthreads();
    for (int t = threadIdx.x; t < NBUCK; t += 256)
        if (h[t]) atomicAdd(&ghist[t], h[t]);
}

// ---- exclusive scan of 782 bucket counts (single block)
__global__ __launch_bounds__(1024) void scan_buckets(const int* __restrict__ ghist,
                                                     int* __restrict__ base,
                                                     int* __restrict__ cursor) {
    __shared__ int sdata[1024];
    int t = threadIdx.x;
    int v = (t < NBUCK) ? ghist[t] : 0;
    sdata[t] = v;
    __syncthreads();
    for (int off = 1; off < 1024; off <<= 1) {
        int add = (t >= off) ? sdata[t - off] : 0;
        __syncthreads();
        sdata[t] += add;
        __syncthreads();
    }
    if (t < NBUCK) { int ex = sdata[t] - v; base[t] = ex; cursor[t] = ex; }
    if (t == 0) base[NBUCK] = N_EDGES;
}

// ---- multisplit into bucket-grouped pk = (dst&127)<<17 | src
__global__ __launch_bounds__(256) void split_kernel(const int* __restrict__ src,
                                                    const int* __restrict__ dst,
                                                    int* __restrict__ cursor,
                                                    int* __restrict__ pk) {
    __shared__ int h[NBUCK];
    __shared__ int lb[NBUCK];
    for (int t = threadIdx.x; t < NBUCK; t += 256) h[t] = 0;
    __syncthreads();
    int beg = blockIdx.x * SPLIT_TILE;
    int end = min(beg + SPLIT_TILE, N_EDGES);
    for (int i = beg + threadIdx.x; i < end; i += 256)
        atomicAdd(&h[dst[i] >> BSHIFT], 1);
    __syncthreads();
    for (int t = threadIdx.x; t < NBUCK; t += 256)
        lb[t] = h[t] ? atomicAdd(&cursor[t], h[t]) : 0;
    __syncthreads();
    for (int t = threadIdx.x; t < NBUCK; t += 256) h[t] = 0;
    __syncthreads();
    for (int i = beg + threadIdx.x; i < end; i += 256) {
        int d = dst[i];
        int b = d >> BSHIFT;
        int off = atomicAdd(&h[b], 1);
        pk[lb[b] + off] = ((d & (NPB - 1)) << 17) | src[i];
    }
}

// ---- per-bucket CSR finalize (LDS count/scan/place)
__global__ __launch_bounds__(256) void bucket_csr(const int* __restrict__ pk,
                                                  const int* __restrict__ base,
                                                  int* __restrict__ row_start,
                                                  int* __restrict__ src_sorted) {
    __shared__ int cnt[NPB];
    __shared__ int cur[NPB];
    const int b = blockIdx.x;
    const int node0 = b << BSHIFT;
    const int ebeg = base[b], eend = base[b + 1];
    int t = threadIdx.x;
    if (t < NPB) cnt[t] = 0;
    __syncthreads();
    for (int e = ebeg + t; e < eend; e += 256)
        atomicAdd(&cnt[pk[e] >> 17], 1);
    __syncthreads();
    int v = (t < NPB) ? cnt[t] : 0;
    for (int off = 1; off < NPB; off <<= 1) {
        int add = (t < NPB && t >= off) ? cnt[t - off] : 0;
        __syncthreads();
        if (t < NPB) cnt[t] += add;
        __syncthreads();
    }
    if (t < NPB) {
        int excl = cnt[t] - v;
        cur[t] = excl;
        int node = node0 + t;
        if (node < N_NODES) row_start[node] = ebeg + excl;
    }
    if (b == NBUCK - 1 && t == 0) row_start[N_NODES] = N_EDGES;
    __syncthreads();
    for (int e = ebeg + t; e < eend; e += 256) {
        int p = pk[e];
        int off = atomicAdd(&cur[p >> 17], 1);
        src_sorted[ebeg + off] = p & 0x1FFFF;
    }
}

// ---- GIN hidden layer, bf16 table. Wave per node. Lane map: g = lane>>3
// (8 edge slots), c = lane&7 (16B chunk = 8 bf16 feats). 16 edges in flight.
// f32 accumulate; readlane matmul with W row per-lane (launch_bounds(256,2)
// gives the VGPR budget so Wc[64] stays RESIDENT — check VGPR_Count!).
__global__ __launch_bounds__(256, 2) void gin_layer_b(
    const unsigned short* __restrict__ in, const int* __restrict__ row_start,
    const int* __restrict__ src_sorted, const float* __restrict__ W,
    const float* __restrict__ bias, unsigned short* __restrict__ outb, int n_nodes) {
    const int lane = threadIdx.x & 63;
    const int g = lane >> 3;
    const int c = lane & 7;
    int wid = (int)((blockIdx.x * blockDim.x + threadIdx.x) >> 6);
    const int nw = (int)((gridDim.x * blockDim.x) >> 6);
    wid = __builtin_amdgcn_readfirstlane(wid);

    const uint4* inv = (const uint4*)in;  // 8 uint4 per 128B row

    float Wc[64];
#pragma unroll
    for (int k = 0; k < 16; ++k) {
        float4 w4 = ((const float4*)(W + lane * 64))[k];
        Wc[4 * k + 0] = w4.x; Wc[4 * k + 1] = w4.y;
        Wc[4 * k + 2] = w4.z; Wc[4 * k + 3] = w4.w;
    }
    const float bj = bias[lane];

    for (int node = wid; node < n_nodes; node += nw) {
        const int e0 = row_start[node];
        const int e1 = row_start[node + 1];

        float a0[8] = {0, 0, 0, 0, 0, 0, 0, 0};
        float a1[8] = {0, 0, 0, 0, 0, 0, 0, 0};
        if (g == 0) acc8(a0, inv[(size_t)node * 8 + c]);

        for (int e = e0; e < e1; e += 16) {
            int i0 = e + g;
            int i1 = e + g + 8;
            if (i0 < e1) acc8(a0, inv[(size_t)src_sorted[i0] * 8 + c]);
            if (i1 < e1) acc8(a1, inv[(size_t)src_sorted[i1] * 8 + c]);
        }
#pragma unroll
        for (int i = 0; i < 8; ++i) {
            a0[i] += a1[i];
            a0[i] += __shfl_xor(a0[i], 8);
            a0[i] += __shfl_xor(a0[i], 16);
            a0[i] += __shfl_xor(a0[i], 32);
        }
        // feat 8*cc+i lives in lane cc (cc=0..7); out[j=lane] = b + sum feat*W
        float acc = bj;
#pragma unroll
        for (int i = 0; i < 8; ++i) {
#pragma unroll
            for (int cc = 0; cc < 8; ++cc) {
                float rv = __int_as_float(__builtin_amdgcn_readlane(__float_as_int(a0[i]), cc));
                acc = fmaf(rv, Wc[8 * cc + i], acc);
            }
        }
        outb[(size_t)node * 64 + lane] = f2bf(fmaxf(acc, 0.0f));
    }
}

// ---- head GEMM: z = h3 @ W4^T, bf16 in, bf16 out (16-padded rows, 32B)
__global__ __launch_bounds__(256, 2) void head_gemm(const unsigned short* __restrict__ in,
                                                    const float* __restrict__ W,
                                                    unsigned short* __restrict__ zb) {
    const int lane = threadIdx.x & 63;
    int wid = (int)((blockIdx.x * blockDim.x + threadIdx.x) >> 6);
    const int nw = (int)((gridDim.x * blockDim.x) >> 6);
    wid = __builtin_amdgcn_readfirstlane(wid);

    const int jc = (lane < 10) ? lane : 0;
    float Wc[64];
#pragma unroll
    for (int k = 0; k < 16; ++k) {
        float4 w4 = ((const float4*)(W + jc * 64))[k];
        Wc[4 * k + 0] = w4.x; Wc[4 * k + 1] = w4.y;
        Wc[4 * k + 2] = w4.z; Wc[4 * k + 3] = w4.w;
    }

    for (int node = wid; node < N_NODES; node += nw) {
        float r = bf2f(in[(size_t)node * 64 + lane]);
        float acc = 0.0f;
#pragma unroll
        for (int k = 0; k < 64; ++k) {
            float rv = __int_as_float(__builtin_amdgcn_readlane(__float_as_int(r), k));
            acc = fmaf(rv, Wc[k], acc);
        }
        if (lane < 16) zb[(size_t)node * 16 + lane] = (lane < 10) ? f2bf(acc) : (unsigned short)0;
    }
}

// ---- head aggregate on bf16 z (32B rows): g = lane>>2 (16 edge slots),
// c = lane&3 (8B chunk = 4 feats). out_i = z_i + sum_j z_j + b.
__global__ __launch_bounds__(256) void head_agg(const unsigned short* __restrict__ zb,
                                                const int* __restrict__ row_start,
                                                const int* __restrict__ src_sorted,
                                                const float* __restrict__ bias,
                                                float* __restrict__ out) {
    const int lane = threadIdx.x & 63;
    const int g = lane >> 2;
    const int c = lane & 3;
    int wid = (int)((blockIdx.x * blockDim.x + threadIdx.x) >> 6);
    const int nw = (int)((gridDim.x * blockDim.x) >> 6);
    wid = __builtin_amdgcn_readfirstlane(wid);

    const uint2* zv = (const uint2*)zb;  // 4 uint2 per 32B row

    for (int node = wid; node < N_NODES; node += nw) {
        const int e0 = row_start[node];
        const int e1 = row_start[node + 1];
        float a0[4] = {0, 0, 0, 0}, a1[4] = {0, 0, 0, 0};
        if (g == 0) {
            uint2 v = zv[(size_t)node * 4 + c];
            a0[0] += __uint_as_float(v.x << 16);
            a0[1] += __uint_as_float(v.x & 0xFFFF0000u);
            a0[2] += __uint_as_float(v.y << 16);
            a0[3] += __uint_as_float(v.y & 0xFFFF0000u);
        }
        for (int e = e0; e < e1; e += 32) {
            int i0 = e + g;
            int i1 = e + g + 16;
            if (i0 < e1) {
                uint2 v = zv[(size_t)src_sorted[i0] * 4 + c];
                a0[0] += __uint_as_float(v.x << 16);
                a0[1] += __uint_as_float(v.x & 0xFFFF0000u);
                a0[2] += __uint_as_float(v.y << 16);
                a0[3] += __uint_as_float(v.y & 0xFFFF0000u);
            }
            if (i1 < e1) {
                uint2 v = zv[(size_t)src_sorted[i1] * 4 + c];
                a1[0] += __uint_as_float(v.x << 16);
                a1[1] += __uint_as_float(v.x & 0xFFFF0000u);
                a1[2] += __uint_as_float(v.y << 16);
                a1[3] += __uint_as_float(v.y & 0xFFFF0000u);
            }
        }
#pragma unroll
        for (int i = 0; i < 4; ++i) {
            a0[i] += a1[i];
            a0[i] += __shfl_xor(a0[i], 4);
            a0[i] += __shfl_xor(a0[i], 8);
            a0[i] += __shfl_xor(a0[i], 16);
            a0[i] += __shfl_xor(a0[i], 32);
        }
        if (g == 0) {
#pragma unroll
            for (int i = 0; i < 4; ++i) {
                int f = 4 * c + i;
                if (f < 10) out[(size_t)node * 10 + f] = a0[i] + bias[f];
            }
        }
    }
}

// ---------------- launcher ----------------

extern "C" void kernel_launch(void* const* d_in, const int* in_sizes, int n_in,
                              void* d_out, int out_size, void* d_ws, size_t ws_size,
                              hipStream_t stream) {
    const float* x  = (const float*)d_in[0];
    const int*   ei = (const int*)d_in[1];
    const int*   src = ei;
    const int*   dst = ei + N_EDGES;
    const float* W1 = (const float*)d_in[2];
    const float* b1 = (const float*)d_in[3];
    const float* W2 = (const float*)d_in[4];
    const float* b2 = (const float*)d_in[5];
    const float* W3 = (const float*)d_in[6];
    const float* b3 = (const float*)d_in[7];
    const float* W4 = (const float*)d_in[8];
    const float* b4 = (const float*)d_in[9];
    float* out = (float*)d_out;

    char* ws = (char*)d_ws;
    size_t off = 0;
    auto carve = [&](size_t bytes) {
        char* p = ws + off;
        off += (bytes + 255) & ~(size_t)255;
        return p;
    };
    int* ghist      = (int*)carve(NBUCK * sizeof(int));
    int* base       = (int*)carve((NBUCK + 1) * sizeof(int));
    int* cursor     = (int*)carve(NBUCK * sizeof(int));
    int* row_start  = (int*)carve((N_NODES + 1) * sizeof(int));
    int* pk         = (int*)carve((size_t)N_EDGES * sizeof(int));
    int* src_sorted = (int*)carve((size_t)N_EDGES * sizeof(int));
    unsigned short* xb  = (unsigned short*)carve((size_t)N_NODES * 64 * 2);
    unsigned short* hb1 = (unsigned short*)carve((size_t)N_NODES * 64 * 2);
    unsigned short* hb2 = (unsigned short*)carve((size_t)N_NODES * 64 * 2);
    // zb (100K x 16 bf16 = 3.2MB) aliases pk (dead after bucket_csr)
    unsigned short* zb  = (unsigned short*)pk;
    (void)ws_size;

    hipMemsetAsync(ghist, 0, NBUCK * sizeof(int), stream);
    cast_to_bf16<<<1024, 256, 0, stream>>>((const float4*)x, (ushort4*)xb, N_NODES * 16);
    hist_kernel<<<64, 256, 0, stream>>>(dst, ghist);
    scan_buckets<<<1, 1024, 0, stream>>>(ghist, base, cursor);
    split_kernel<<<SPLIT_BLOCKS, 256, 0, stream>>>(src, dst, cursor, pk);
    bucket_csr<<<NBUCK, 256, 0, stream>>>(pk, base, row_start, src_sorted);

    gin_layer_b<<<2048, 256, 0, stream>>>(xb,  row_start, src_sorted, W1, b1, hb1, N_NODES);
    gin_layer_b<<<2048, 256, 0, stream>>>(hb1, row_start, src_sorted, W2, b2, hb2, N_NODES);
    gin_layer_b<<<2048, 256, 0, stream>>>(hb2, row_start, src_sorted, W3, b3, hb1, N_NODES);
    head_gemm<<<1024, 256, 0, stream>>>(hb1, W4, zb);
    head_agg<<<2048, 256, 0, stream>>>(zb, row_start, src_sorted, b4, out);
}

// Round 13
// 357.548 us; speedup vs baseline: 8.2041x; 1.4477x over previous
//
#include <hip/hip_runtime.h>

#define N_NODES 100000
#define N_EDGES 1600000
#define BSHIFT 7
#define NPB 128
#define NBUCK ((N_NODES + NPB - 1) / NPB)         // 782

#define SPLIT_TILE 8192
#define SPLIT_BLOCKS ((N_EDGES + SPLIT_TILE - 1) / SPLIT_TILE)  // 196

typedef __attribute__((ext_vector_type(8))) short bf16x8;
typedef __attribute__((ext_vector_type(4))) float f32x4;

__device__ __forceinline__ unsigned short f2bf(float f) {
    unsigned u = __float_as_uint(f);
    unsigned r = (u + 0x7FFFu + ((u >> 16) & 1u)) >> 16;
    return (unsigned short)r;
}
__device__ __forceinline__ void acc8(float* a, uint4 v) {
    a[0] += __uint_as_float(v.x << 16);
    a[1] += __uint_as_float(v.x & 0xFFFF0000u);
    a[2] += __uint_as_float(v.y << 16);
    a[3] += __uint_as_float(v.y & 0xFFFF0000u);
    a[4] += __uint_as_float(v.z << 16);
    a[5] += __uint_as_float(v.z & 0xFFFF0000u);
    a[6] += __uint_as_float(v.w << 16);
    a[7] += __uint_as_float(v.w & 0xFFFF0000u);
}
__device__ __forceinline__ bf16x8 as_bf16x8(uint4 v) {
    union { uint4 u; bf16x8 b; } x; x.u = v; return x.b;
}

// ---- x (f32) -> bf16
__global__ __launch_bounds__(256) void cast_to_bf16(const float4* __restrict__ in,
                                                    ushort4* __restrict__ outv, int n4) {
    int i = blockIdx.x * 256 + threadIdx.x;
    int stride = gridDim.x * 256;
    for (; i < n4; i += stride) {
        float4 v = in[i];
        ushort4 o;
        o.x = f2bf(v.x); o.y = f2bf(v.y); o.z = f2bf(v.z); o.w = f2bf(v.w);
        outv[i] = o;
    }
}

// ---- weights -> bf16 (W4 zero-padded to 16 rows)
__global__ __launch_bounds__(256) void cast_weights(
    const float* __restrict__ W1, const float* __restrict__ W2,
    const float* __restrict__ W3, const float* __restrict__ W4,
    unsigned short* __restrict__ Wb1, unsigned short* __restrict__ Wb2,
    unsigned short* __restrict__ Wb3, unsigned short* __restrict__ Wb4) {
    int t = blockIdx.x * 256 + threadIdx.x;
    if (t < 4096) {
        Wb1[t] = f2bf(W1[t]); Wb2[t] = f2bf(W2[t]); Wb3[t] = f2bf(W3[t]);
    }
    if (t < 1024) Wb4[t] = (t < 640) ? f2bf(W4[t]) : (unsigned short)0;
}

// ---- bucket histogram
__global__ __launch_bounds__(256) void hist_kernel(const int* __restrict__ dst,
                                                   int* __restrict__ ghist) {
    __shared__ int h[NBUCK];
    for (int t = threadIdx.x; t < NBUCK; t += 256) h[t] = 0;
    __syncthreads();
    int i = blockIdx.x * 256 + threadIdx.x;
    int stride = gridDim.x * 256;
    for (; i < N_EDGES; i += stride) atomicAdd(&h[dst[i] >> BSHIFT], 1);
    __syncthreads();
    for (int t = threadIdx.x; t < NBUCK; t += 256)
        if (h[t]) atomicAdd(&ghist[t], h[t]);
}

// ---- exclusive scan of bucket counts
__global__ __launch_bounds__(1024) void scan_buckets(const int* __restrict__ ghist,
                                                     int* __restrict__ base,
                                                     int* __restrict__ cursor) {
    __shared__ int sdata[1024];
    int t = threadIdx.x;
    int v = (t < NBUCK) ? ghist[t] : 0;
    sdata[t] = v;
    __syncthreads();
    for (int off = 1; off < 1024; off <<= 1) {
        int add = (t >= off) ? sdata[t - off] : 0;
        __syncthreads();
        sdata[t] += add;
        __syncthreads();
    }
    if (t < NBUCK) { int ex = sdata[t] - v; base[t] = ex; cursor[t] = ex; }
    if (t == 0) base[NBUCK] = N_EDGES;
}

// ---- multisplit into bucket-grouped pk = (dst&127)<<17 | src
__global__ __launch_bounds__(256) void split_kernel(const int* __restrict__ src,
                                                    const int* __restrict__ dst,
                                                    int* __restrict__ cursor,
                                                    int* __restrict__ pk) {
    __shared__ int h[NBUCK];
    __shared__ int lb[NBUCK];
    for (int t = threadIdx.x; t < NBUCK; t += 256) h[t] = 0;
    __syncthreads();
    int beg = blockIdx.x * SPLIT_TILE;
    int end = min(beg + SPLIT_TILE, N_EDGES);
    for (int i = beg + threadIdx.x; i < end; i += 256)
        atomicAdd(&h[dst[i] >> BSHIFT], 1);
    __syncthreads();
    for (int t = threadIdx.x; t < NBUCK; t += 256)
        lb[t] = h[t] ? atomicAdd(&cursor[t], h[t]) : 0;
    __syncthreads();
    for (int t = threadIdx.x; t < NBUCK; t += 256) h[t] = 0;
    __syncthreads();
    for (int i = beg + threadIdx.x; i < end; i += 256) {
        int d = dst[i];
        int b = d >> BSHIFT;
        int off = atomicAdd(&h[b], 1);
        pk[lb[b] + off] = ((d & (NPB - 1)) << 17) | src[i];
    }
}

// ---- per-bucket CSR finalize
__global__ __launch_bounds__(256) void bucket_csr(const int* __restrict__ pk,
                                                  const int* __restrict__ base,
                                                  int* __restrict__ row_start,
                                                  int* __restrict__ src_sorted) {
    __shared__ int cnt[NPB];
    __shared__ int cur[NPB];
    const int b = blockIdx.x;
    const int node0 = b << BSHIFT;
    const int ebeg = base[b], eend = base[b + 1];
    int t = threadIdx.x;
    if (t < NPB) cnt[t] = 0;
    __syncthreads();
    for (int e = ebeg + t; e < eend; e += 256)
        atomicAdd(&cnt[pk[e] >> 17], 1);
    __syncthreads();
    int v = (t < NPB) ? cnt[t] : 0;
    for (int off = 1; off < NPB; off <<= 1) {
        int add = (t < NPB && t >= off) ? cnt[t - off] : 0;
        __syncthreads();
        if (t < NPB) cnt[t] += add;
        __syncthreads();
    }
    if (t < NPB) {
        int excl = cnt[t] - v;
        cur[t] = excl;
        int node = node0 + t;
        if (node < N_NODES) row_start[node] = ebeg + excl;
    }
    if (b == NBUCK - 1 && t == 0) row_start[N_NODES] = N_EDGES;
    __syncthreads();
    for (int e = ebeg + t; e < eend; e += 256) {
        int p = pk[e];
        int off = atomicAdd(&cur[p >> 17], 1);
        src_sorted[ebeg + off] = p & 0x1FFFF;
    }
}

// ---- pure gather-aggregate: agg[n] = in[n] + sum_{j->n} in[j], bf16 in/out.
// Wave per 2 nodes interleaved (4 independent 1KB gather chains in flight).
// Lane map: g = lane>>3 (edge slot), c = lane&7 (16B chunk).
__global__ __launch_bounds__(256) void agg_kernel(
    const unsigned short* __restrict__ in, const int* __restrict__ row_start,
    const int* __restrict__ src_sorted, unsigned short* __restrict__ outb) {
    const int lane = threadIdx.x & 63;
    const int g = lane >> 3;
    const int c = lane & 7;
    int wid = (int)((blockIdx.x * blockDim.x + threadIdx.x) >> 6);
    const int nw = (int)((gridDim.x * blockDim.x) >> 6);
    wid = __builtin_amdgcn_readfirstlane(wid);

    const uint4* inv = (const uint4*)in;
    uint4* outv = (uint4*)outb;

    for (int nA = wid; nA < N_NODES; nA += 2 * nw) {
        const int nB = nA + nw;
        const bool hasB = nB < N_NODES;
        int eA = row_start[nA];
        const int eA1 = row_start[nA + 1];
        int eB = hasB ? row_start[nB] : 0;
        const int eB1 = hasB ? row_start[nB + 1] : 0;

        float aA0[8] = {0,0,0,0,0,0,0,0}, aA1[8] = {0,0,0,0,0,0,0,0};
        float aB0[8] = {0,0,0,0,0,0,0,0}, aB1[8] = {0,0,0,0,0,0,0,0};
        if (g == 0) {
            acc8(aA0, inv[(size_t)nA * 8 + c]);
            if (hasB) acc8(aB0, inv[(size_t)nB * 8 + c]);
        }
        for (; eA < eA1 || eB < eB1; eA += 16, eB += 16) {
            int iA0 = eA + g, iA1 = eA + g + 8;
            int iB0 = eB + g, iB1 = eB + g + 8;
            if (iA0 < eA1) acc8(aA0, inv[(size_t)src_sorted[iA0] * 8 + c]);
            if (iA1 < eA1) acc8(aA1, inv[(size_t)src_sorted[iA1] * 8 + c]);
            if (iB0 < eB1) acc8(aB0, inv[(size_t)src_sorted[iB0] * 8 + c]);
            if (iB1 < eB1) acc8(aB1, inv[(size_t)src_sorted[iB1] * 8 + c]);
        }
#pragma unroll
        for (int i = 0; i < 8; ++i) {
            aA0[i] += aA1[i];
            aA0[i] += __shfl_xor(aA0[i], 8);
            aA0[i] += __shfl_xor(aA0[i], 16);
            aA0[i] += __shfl_xor(aA0[i], 32);
            aB0[i] += aB1[i];
            aB0[i] += __shfl_xor(aB0[i], 8);
            aB0[i] += __shfl_xor(aB0[i], 16);
            aB0[i] += __shfl_xor(aB0[i], 32);
        }
        if (g == 0) {
            uint4 o;
            o.x = (unsigned)f2bf(aA0[0]) | ((unsigned)f2bf(aA0[1]) << 16);
            o.y = (unsigned)f2bf(aA0[2]) | ((unsigned)f2bf(aA0[3]) << 16);
            o.z = (unsigned)f2bf(aA0[4]) | ((unsigned)f2bf(aA0[5]) << 16);
            o.w = (unsigned)f2bf(aA0[6]) | ((unsigned)f2bf(aA0[7]) << 16);
            outv[(size_t)nA * 8 + c] = o;
            if (hasB) {
                uint4 p;
                p.x = (unsigned)f2bf(aB0[0]) | ((unsigned)f2bf(aB0[1]) << 16);
                p.y = (unsigned)f2bf(aB0[2]) | ((unsigned)f2bf(aB0[3]) << 16);
                p.z = (unsigned)f2bf(aB0[4]) | ((unsigned)f2bf(aB0[5]) << 16);
                p.w = (unsigned)f2bf(aB0[6]) | ((unsigned)f2bf(aB0[7]) << 16);
                outv[(size_t)nB * 8 + c] = p;
            }
        }
    }
}

// ---- MFMA GEMM: out[n][j] = act(A[n][:] . Wb[j][:] + bias[j]), bf16 in/out.
// Per wave: 16-node x 16-j tile, K=64 via 2 mfma_f32_16x16x32_bf16.
// A frag: m=lane&15 (node), k=(lane>>4)*8+i. B frag: n=lane&15 (j), same k.
// C/D: col(j)=lane&15, row(node)=(lane>>4)*4+reg  [m89-verified layout].
template <int NJ, bool RELU, bool BIAS>
__global__ __launch_bounds__(256) void gemm_kernel(
    const unsigned short* __restrict__ A, const unsigned short* __restrict__ Wb,
    const float* __restrict__ bias, unsigned short* __restrict__ out) {
    const int lane = threadIdx.x & 63;
    const int wave = threadIdx.x >> 6;
    const int m = lane & 15;
    const int kg = lane >> 4;
    const int node0 = blockIdx.x * 64 + wave * 16;
    if (node0 >= N_NODES) return;

    const uint4* Arow = (const uint4*)(A + (size_t)(node0 + m) * 64);
    uint4 a0 = Arow[kg];        // k = kg*8 .. +7
    uint4 a1 = Arow[4 + kg];    // k = 32 + kg*8 .. +7

#pragma unroll
    for (int j0 = 0; j0 < NJ; j0 += 16) {
        const uint4* Brow = (const uint4*)(Wb + (size_t)(j0 + m) * 64);
        uint4 b0 = Brow[kg];
        uint4 b1 = Brow[4 + kg];
        f32x4 acc = {0.f, 0.f, 0.f, 0.f};
        acc = __builtin_amdgcn_mfma_f32_16x16x32_bf16(as_bf16x8(a0), as_bf16x8(b0), acc, 0, 0, 0);
        acc = __builtin_amdgcn_mfma_f32_16x16x32_bf16(as_bf16x8(a1), as_bf16x8(b1), acc, 0, 0, 0);
        const float bj = BIAS ? bias[j0 + m] : 0.0f;
#pragma unroll
        for (int r = 0; r < 4; ++r) {
            int node = node0 + kg * 4 + r;
            if (node < N_NODES) {
                float v = acc[r] + bj;
                if (RELU) v = fmaxf(v, 0.0f);
                out[(size_t)node * NJ + j0 + m] = f2bf(v);
            }
        }
    }
}

// ---- head aggregate on bf16 z (32B rows, 16-wide padded)
__global__ __launch_bounds__(256) void head_agg(const unsigned short* __restrict__ zb,
                                                const int* __restrict__ row_start,
                                                const int* __restrict__ src_sorted,
                                                const float* __restrict__ bias,
                                                float* __restrict__ out) {
    const int lane = threadIdx.x & 63;
    const int g = lane >> 2;
    const int c = lane & 3;
    int wid = (int)((blockIdx.x * blockDim.x + threadIdx.x) >> 6);
    const int nw = (int)((gridDim.x * blockDim.x) >> 6);
    wid = __builtin_amdgcn_readfirstlane(wid);

    const uint2* zv = (const uint2*)zb;

    for (int node = wid; node < N_NODES; node += nw) {
        const int e0 = row_start[node];
        const int e1 = row_start[node + 1];
        float a0[4] = {0, 0, 0, 0}, a1[4] = {0, 0, 0, 0};
        if (g == 0) {
            uint2 v = zv[(size_t)node * 4 + c];
            a0[0] += __uint_as_float(v.x << 16);
            a0[1] += __uint_as_float(v.x & 0xFFFF0000u);
            a0[2] += __uint_as_float(v.y << 16);
            a0[3] += __uint_as_float(v.y & 0xFFFF0000u);
        }
        for (int e = e0; e < e1; e += 32) {
            int i0 = e + g;
            int i1 = e + g + 16;
            if (i0 < e1) {
                uint2 v = zv[(size_t)src_sorted[i0] * 4 + c];
                a0[0] += __uint_as_float(v.x << 16);
                a0[1] += __uint_as_float(v.x & 0xFFFF0000u);
                a0[2] += __uint_as_float(v.y << 16);
                a0[3] += __uint_as_float(v.y & 0xFFFF0000u);
            }
            if (i1 < e1) {
                uint2 v = zv[(size_t)src_sorted[i1] * 4 + c];
                a1[0] += __uint_as_float(v.x << 16);
                a1[1] += __uint_as_float(v.x & 0xFFFF0000u);
                a1[2] += __uint_as_float(v.y << 16);
                a1[3] += __uint_as_float(v.y & 0xFFFF0000u);
            }
        }
#pragma unroll
        for (int i = 0; i < 4; ++i) {
            a0[i] += a1[i];
            a0[i] += __shfl_xor(a0[i], 4);
            a0[i] += __shfl_xor(a0[i], 8);
            a0[i] += __shfl_xor(a0[i], 16);
            a0[i] += __shfl_xor(a0[i], 32);
        }
        if (g == 0) {
#pragma unroll
            for (int i = 0; i < 4; ++i) {
                int f = 4 * c + i;
                if (f < 10) out[(size_t)node * 10 + f] = a0[i] + bias[f];
            }
        }
    }
}

// ---------------- launcher ----------------

extern "C" void kernel_launch(void* const* d_in, const int* in_sizes, int n_in,
                              void* d_out, int out_size, void* d_ws, size_t ws_size,
                              hipStream_t stream) {
    const float* x  = (const float*)d_in[0];
    const int*   ei = (const int*)d_in[1];
    const int*   src = ei;
    const int*   dst = ei + N_EDGES;
    const float* W1 = (const float*)d_in[2];
    const float* b1 = (const float*)d_in[3];
    const float* W2 = (const float*)d_in[4];
    const float* b2 = (const float*)d_in[5];
    const float* W3 = (const float*)d_in[6];
    const float* b3 = (const float*)d_in[7];
    const float* W4 = (const float*)d_in[8];
    const float* b4 = (const float*)d_in[9];
    float* out = (float*)d_out;

    char* ws = (char*)d_ws;
    size_t off = 0;
    auto carve = [&](size_t bytes) {
        char* p = ws + off;
        off += (bytes + 255) & ~(size_t)255;
        return p;
    };
    const size_t ROWS = (size_t)N_NODES + 64;   // +64 rows pad for GEMM tile reads
    int* ghist      = (int*)carve(NBUCK * sizeof(int));
    int* base       = (int*)carve((NBUCK + 1) * sizeof(int));
    int* cursor     = (int*)carve(NBUCK * sizeof(int));
    int* row_start  = (int*)carve((N_NODES + 1) * sizeof(int));
    int* pk         = (int*)carve((size_t)N_EDGES * sizeof(int));
    int* src_sorted = (int*)carve((size_t)N_EDGES * sizeof(int));
    unsigned short* ag  = (unsigned short*)carve(ROWS * 64 * 2);
    unsigned short* hA  = (unsigned short*)carve(ROWS * 64 * 2);
    unsigned short* hB  = (unsigned short*)carve(ROWS * 64 * 2);   // also holds xb
    unsigned short* Wb1 = (unsigned short*)carve(4096 * 2);
    unsigned short* Wb2 = (unsigned short*)carve(4096 * 2);
    unsigned short* Wb3 = (unsigned short*)carve(4096 * 2);
    unsigned short* Wb4 = (unsigned short*)carve(1024 * 2);
    unsigned short* zb  = (unsigned short*)pk;   // pk dead after bucket_csr
    unsigned short* xb  = hB;
    (void)ws_size;

    const int GB = (N_NODES + 63) / 64;  // 1563 gemm blocks

    hipMemsetAsync(ghist, 0, NBUCK * sizeof(int), stream);
    cast_to_bf16<<<1024, 256, 0, stream>>>((const float4*)x, (ushort4*)xb, N_NODES * 16);
    cast_weights<<<16, 256, 0, stream>>>(W1, W2, W3, W4, Wb1, Wb2, Wb3, Wb4);
    hist_kernel<<<256, 256, 0, stream>>>(dst, ghist);
    scan_buckets<<<1, 1024, 0, stream>>>(ghist, base, cursor);
    split_kernel<<<SPLIT_BLOCKS, 256, 0, stream>>>(src, dst, cursor, pk);
    bucket_csr<<<NBUCK, 256, 0, stream>>>(pk, base, row_start, src_sorted);

    agg_kernel<<<2048, 256, 0, stream>>>(xb, row_start, src_sorted, ag);
    gemm_kernel<64, true, true><<<GB, 256, 0, stream>>>(ag, Wb1, b1, hA);
    agg_kernel<<<2048, 256, 0, stream>>>(hA, row_start, src_sorted, ag);
    gemm_kernel<64, true, true><<<GB, 256, 0, stream>>>(ag, Wb2, b2, hB);
    agg_kernel<<<2048, 256, 0, stream>>>(hB, row_start, src_sorted, ag);
    gemm_kernel<64, true, true><<<GB, 256, 0, stream>>>(ag, Wb3, b3, hA);
    gemm_kernel<16, false, false><<<GB, 256, 0, stream>>>(hA, Wb4, b4, zb);
    head_agg<<<2048, 256, 0, stream>>>(zb, row_start, src_sorted, b4, out);
}